// Round 5
// baseline (21.527 us; speedup 1.0000x reference)
//
#include <hip/hip_runtime.h>

// Bootstrap proposal (time != 0 branch), constants folded for L1=L2=M1=M2=1.
// Per particle [tq1, tq2, th1, th2, v1, v2]:
//   c  = cos(th2)
//   a1 = (12*tq1 - 6*(3c+2)*tq2) / (16 - 9c^2)
//   a2 = (12*(5+3c)*tq2 - 6*(3c+2)*tq1) / (16 - 9c^2)
//   mean = prev + DT*[0, 0, v1, v2, a1, a2]
//
// AoS [B*P, 6] f32; one thread computes one particle PAIR (48 B = 3 float4).
// Wave-local LDS transpose: each wave owns 192-float4 tiles (64 pairs), so
// the LDS write->read dependency is within one wave and needs only
// s_waitcnt lgkmcnt(0) -- NO __syncthreads. Per-wave LDS ops retire in
// order, so stage-2 writes can't pass stage-1 reads. Global traffic is
// lane-contiguous float4 with nontemporal hints (read-once/write-once).
// ext_vector_type because nontemporal builtins reject HIP_vector_type;
// scalar locals because clang can't bind refs to vector elements.

#define DT 0.01f

typedef float f4 __attribute__((ext_vector_type(4)));

#define LGKM0() asm volatile("s_waitcnt lgkmcnt(0)" ::: "memory")

struct Six { float m0, m1, m2, m3, m4, m5; };

__device__ __forceinline__ Six particle_step(
    float tq1, float tq2, float th1, float th2, float v1, float v2) {
    const float c    = cosf(th2);
    const float rden = 1.0f / (16.0f - 9.0f * c * c);   // = 1/(36*det)
    const float s    = 6.0f * (3.0f * c + 2.0f);        // = 36*d01
    const float a1   = (12.0f * tq1 - s * tq2) * rden;
    const float a2   = (12.0f * (5.0f + 3.0f * c) * tq2 - s * tq1) * rden;
    Six r;
    r.m0 = tq1;
    r.m1 = tq2;
    r.m2 = th1 + DT * v1;
    r.m3 = th2 + DT * v2;
    r.m4 = v1 + DT * a1;
    r.m5 = v2 + DT * a2;
    return r;
}

__device__ __forceinline__ void pair_step(const f4 v0, const f4 v1,
                                          const f4 v2, f4& o0,
                                          f4& o1, f4& o2) {
    const Six p = particle_step(v0.x, v0.y, v0.z, v0.w, v1.x, v1.y);
    const Six q = particle_step(v1.z, v1.w, v2.x, v2.y, v2.z, v2.w);
    f4 t0, t1, t2;
    t0.x = p.m0; t0.y = p.m1; t0.z = p.m2; t0.w = p.m3;
    t1.x = p.m4; t1.y = p.m5; t1.z = q.m0; t1.w = q.m1;
    t2.x = q.m2; t2.y = q.m3; t2.z = q.m4; t2.w = q.m5;
    o0 = t0; o1 = t1; o2 = t2;
}

// 256 threads = 4 waves; each wave handles 2 tiles of 192 float4 (64 pairs).
// Block covers 1536 float4 = 24 KB LDS.
__global__ void __launch_bounds__(256)
bootstrap_proposal_kernel(const f4* __restrict__ in4,
                          f4* __restrict__ out4,
                          long long nvec) {
    __shared__ f4 lds[1536];
    const int t    = threadIdx.x;
    const int w    = t >> 6;        // wave 0..3
    const int lane = t & 63;
    const long long base = (long long)blockIdx.x * 1536;

    const int tile0 = w * 192;          // wave-owned LDS regions
    const int tile1 = 768 + w * 192;

    // Stage 1: coalesced global -> LDS (6 independent loads in flight)
#pragma unroll
    for (int j = 0; j < 3; ++j) {
        const long long i0 = base + tile0 + j * 64 + lane;
        const long long i1 = base + tile1 + j * 64 + lane;
        if (i0 < nvec) lds[tile0 + j * 64 + lane] = __builtin_nontemporal_load(&in4[i0]);
        if (i1 < nvec) lds[tile1 + j * 64 + lane] = __builtin_nontemporal_load(&in4[i1]);
    }
    LGKM0();  // wave-local: writes visible to this wave's reads

    // Stage 2: each lane reads its 2 pairs (48 B lane stride: conflict-free
    // b128 pattern), computes, writes back in place.
    const f4 a0 = lds[tile0 + 3 * lane + 0];
    const f4 a1 = lds[tile0 + 3 * lane + 1];
    const f4 a2 = lds[tile0 + 3 * lane + 2];
    const f4 b0 = lds[tile1 + 3 * lane + 0];
    const f4 b1 = lds[tile1 + 3 * lane + 1];
    const f4 b2 = lds[tile1 + 3 * lane + 2];

    f4 oa0, oa1, oa2, ob0, ob1, ob2;
    pair_step(a0, a1, a2, oa0, oa1, oa2);
    pair_step(b0, b1, b2, ob0, ob1, ob2);

    lds[tile0 + 3 * lane + 0] = oa0;
    lds[tile0 + 3 * lane + 1] = oa1;
    lds[tile0 + 3 * lane + 2] = oa2;
    lds[tile1 + 3 * lane + 0] = ob0;
    lds[tile1 + 3 * lane + 1] = ob1;
    lds[tile1 + 3 * lane + 2] = ob2;
    LGKM0();

    // Stage 3: coalesced LDS -> global, nontemporal (write-once stream)
#pragma unroll
    for (int j = 0; j < 3; ++j) {
        const long long i0 = base + tile0 + j * 64 + lane;
        const long long i1 = base + tile1 + j * 64 + lane;
        if (i0 < nvec) __builtin_nontemporal_store(lds[tile0 + j * 64 + lane], &out4[i0]);
        if (i1 < nvec) __builtin_nontemporal_store(lds[tile1 + j * 64 + lane], &out4[i1]);
    }
}

extern "C" void kernel_launch(void* const* d_in, const int* in_sizes, int n_in,
                              void* d_out, int out_size, void* d_ws, size_t ws_size,
                              hipStream_t stream) {
    const float* in = (const float*)d_in[0];   // [B*P, 6] f32
    float* out = (float*)d_out;                // [B*P, 6] f32
    const long long nvec = (long long)out_size / 4;         // total float4
    const int grid = (int)((nvec + 1535) / 1536);           // 1536 float4/block
    bootstrap_proposal_kernel<<<grid, 256, 0, stream>>>(
        (const f4*)in, (f4*)out, nvec);
}

// Round 6
// 20.704 us; speedup vs baseline: 1.0397x; 1.0397x over previous
//
#include <hip/hip_runtime.h>

// Bootstrap proposal (time != 0 branch), constants folded for L1=L2=M1=M2=1.
// Per particle [tq1, tq2, th1, th2, v1, v2]:
//   c  = cos(th2)
//   acc1 = (12*tq1 - 6*(3c+2)*tq2) / (16 - 9c^2)
//   acc2 = (12*(5+3c)*tq2 - 6*(3c+2)*tq1) / (16 - 9c^2)
//   mean = prev + DT*[0, 0, v1, v2, acc1, acc2]
//
// AoS [B*P, 6] f32 = groups of 3 float4 per 2 particles:
//   i0 = [tq1 tq2 th1 th2]   i1 = [v1 v2 tq1' tq2']   i2 = [th1' th2' v1' v2']
// Each OUTPUT float4 needs only itself + one neighbor:
//   o0 = [i0.x, i0.y, i0.z+DT*i1.x, i0.w+DT*i1.y]          (self=i0, nb=i1=+1)
//   o1 = [i1.x+DT*acc1, i1.y+DT*acc2, i1.z, i1.w]           (self=i1, nb=i0=-1)
//   o2 = [i2.x+DT*i2.z, i2.y+DT*i2.w, i2.z+DT*acc1',
//         i2.w+DT*acc2']                                    (self=i2, nb=i1=-1)
// -> one thread per output float4: 2 overlapping-contiguous loads, select-based
// phase math (no divergence), 1 contiguous nontemporal store. No LDS, no sync.
// Phase-0 lanes evaluate cos/accel on dummy-but-finite args (den in [7,25]).

#define DT 0.01f

typedef float f4 __attribute__((ext_vector_type(4)));

__global__ void __launch_bounds__(256)
bootstrap_proposal_kernel(const f4* __restrict__ in4,
                          f4* __restrict__ out4,
                          int nvec) {
    const int idx = blockIdx.x * 256 + threadIdx.x;
    if (idx >= nvec) return;

    const int phase = idx % 3;               // 0,1,2 within the 2-particle group
    const f4 a = in4[idx];                   // self
    const f4 b = in4[idx + ((phase == 0) ? 1 : -1)];  // neighbor

    // accel inputs: phase1 -> tq=b.xy, th2=b.w ; phase2 -> tq=b.zw, th2=a.y
    const float th2  = (phase == 1) ? b.w : a.y;
    const float tq1  = (phase == 1) ? b.x : b.z;
    const float tq2  = (phase == 1) ? b.y : b.w;
    const float c    = cosf(th2);
    const float rden = 1.0f / (16.0f - 9.0f * c * c);   // = 1/(36*det)
    const float s    = 6.0f * (3.0f * c + 2.0f);        // = 36*d01
    const float acc1 = (12.0f * tq1 - s * tq2) * rden;
    const float acc2 = (12.0f * (5.0f + 3.0f * c) * tq2 - s * tq1) * rden;

    // o = a + DT * sel, per component:
    const float sx = (phase == 0) ? 0.0f : ((phase == 1) ? acc1 : a.z);
    const float sy = (phase == 0) ? 0.0f : ((phase == 1) ? acc2 : a.w);
    const float sz = (phase == 0) ? b.x  : ((phase == 1) ? 0.0f : acc1);
    const float sw = (phase == 0) ? b.y  : ((phase == 1) ? 0.0f : acc2);

    f4 o;
    o.x = a.x + DT * sx;
    o.y = a.y + DT * sy;
    o.z = a.z + DT * sz;
    o.w = a.w + DT * sw;
    __builtin_nontemporal_store(o, &out4[idx]);
}

extern "C" void kernel_launch(void* const* d_in, const int* in_sizes, int n_in,
                              void* d_out, int out_size, void* d_ws, size_t ws_size,
                              hipStream_t stream) {
    const float* in = (const float*)d_in[0];   // [B*P, 6] f32
    float* out = (float*)d_out;                // [B*P, 6] f32
    const int nvec = out_size / 4;             // total float4 (divisible by 3)
    const int grid = (nvec + 255) / 256;
    bootstrap_proposal_kernel<<<grid, 256, 0, stream>>>(
        (const f4*)in, (f4*)out, nvec);
}